// Round 1
// baseline (1459.636 us; speedup 1.0000x reference)
//
#include <hip/hip_runtime.h>
#include <math.h>

// Problem constants (B, SY, SX, D from reference)
constexpr int Bn = 16, SY = 2048, SX = 2048, Dd = 128;
constexpr int YT = 32;   // y rows per block
constexpr int XT = 32;   // x cols per tile

__global__ void zero_kernel(float* __restrict__ p, int n) {
  int i = blockIdx.x * 256 + threadIdx.x;
  if (i < n) p[i] = 0.f;
}

// One block = (batch b, 32 consecutive y rows). Flash-style online softmax
// over 64 x-tiles of 32. LDS ~56 KB -> 2 blocks/CU.
__launch_bounds__(256, 2)
__global__ void attn_kernel(const float* __restrict__ x, const float* __restrict__ y,
                            float* __restrict__ visual, float* __restrict__ out) {
  const int t = threadIdx.x;
  constexpr int nYB = SY / YT;                 // 64 blocks per batch
  const int b  = blockIdx.x / nYB;
  const int y0 = (blockIdx.x % nYB) * YT;

  __shared__ float ysT[Dd][YT + 4];   // y tile, d-major, +4 pad (bank + 16B align)
  __shared__ float xsT[Dd][XT + 4];   // x tile, d-major (for S = y.xT)
  __shared__ float xsR[XT][Dd];       // x tile, row-major (for O += P.x)
  __shared__ float S[YT][XT + 1];     // scores, then P = exp(S - m)
  __shared__ float alpha_s[YT];
  __shared__ float l_s[YT];

  // ---- load y tile (transposed). Global reads coalesced (d fastest). ----
  const float* yb = y + ((size_t)b * SY + y0) * Dd;
  #pragma unroll
  for (int i = 0; i < (YT * Dd) / 256; ++i) {
    int idx = i * 256 + t;
    ysT[idx & (Dd - 1)][idx >> 7] = yb[idx];
  }

  // online-softmax state: thread t < YT owns row t
  float m_i = -INFINITY, l_i = 0.f;

  // O accumulator: thread owns 4 y-rows (yg*4..+3) x 4 d (dc..dc+3)
  const int yg = t >> 5;            // 0..7
  const int dc = (t & 31) * 4;      // 0..124
  float o[4][4];
  #pragma unroll
  for (int i = 0; i < 4; ++i)
    #pragma unroll
    for (int j = 0; j < 4; ++j) o[i][j] = 0.f;

  const float* xb = x + (size_t)b * SX * Dd;
  constexpr float inv_SY = 1.0f / (float)SY;

  for (int xt = 0; xt < SX / XT; ++xt) {
    __syncthreads();   // previous iteration's readers done before overwrite

    // ---- stage x tile in both layouts ----
    const float* xp = xb + (size_t)xt * XT * Dd;
    #pragma unroll
    for (int i = 0; i < (XT * Dd) / 256; ++i) {
      int idx = i * 256 + t;
      int xx = idx >> 7, dd = idx & (Dd - 1);
      float v = xp[idx];
      xsT[dd][xx] = v;
      xsR[xx][dd] = v;
    }
    __syncthreads();

    // ---- S[yy][xx] = sum_d y[yy][d] * x[xx][d] ----
    {
      const int ty = t >> 5;        // 4 rows: ty*4..+3
      const int tx = t & 31;        // 1 col
      float a0 = 0.f, a1 = 0.f, a2 = 0.f, a3 = 0.f;
      for (int dd = 0; dd < Dd; ++dd) {
        float xv = xsT[dd][tx];
        const float* yr = &ysT[dd][ty * 4];   // 16B-aligned, contiguous 4
        a0 += yr[0] * xv; a1 += yr[1] * xv; a2 += yr[2] * xv; a3 += yr[3] * xv;
      }
      S[ty * 4 + 0][tx] = a0; S[ty * 4 + 1][tx] = a1;
      S[ty * 4 + 2][tx] = a2; S[ty * 4 + 3][tx] = a3;
    }
    __syncthreads();

    // ---- phase A (reads only): visual col-sums + row max ----
    float m_new = m_i;
    if (t < XT) {  // column t: mean over y of RAW scores
      float cs = 0.f;
      #pragma unroll 4
      for (int yy = 0; yy < YT; ++yy) cs += S[yy][t];
      atomicAdd(&visual[(size_t)b * SX + xt * XT + t], cs * inv_SY);
    }
    if (t < YT) {  // row t: running max
      #pragma unroll 4
      for (int xx = 0; xx < XT; ++xx) m_new = fmaxf(m_new, S[t][xx]);
      alpha_s[t] = __expf(m_i - m_new);   // 0 on first tile (m_i = -inf)
    }
    __syncthreads();

    // ---- phase B: P = exp(S - m_new), l update ----
    if (t < YT) {
      float rs = 0.f;
      #pragma unroll 4
      for (int xx = 0; xx < XT; ++xx) {
        float e = __expf(S[t][xx] - m_new);
        S[t][xx] = e;
        rs += e;
      }
      l_i = l_i * __expf(m_i - m_new) + rs;
      m_i = m_new;
    }
    __syncthreads();

    // ---- O = O*alpha + P @ x ----
    {
      float a0 = alpha_s[yg * 4 + 0], a1 = alpha_s[yg * 4 + 1];
      float a2 = alpha_s[yg * 4 + 2], a3 = alpha_s[yg * 4 + 3];
      #pragma unroll
      for (int j = 0; j < 4; ++j) {
        o[0][j] *= a0; o[1][j] *= a1; o[2][j] *= a2; o[3][j] *= a3;
      }
      for (int xx = 0; xx < XT; ++xx) {
        float p0 = S[yg * 4 + 0][xx], p1 = S[yg * 4 + 1][xx];
        float p2 = S[yg * 4 + 2][xx], p3 = S[yg * 4 + 3][xx];
        float4 xv = *(const float4*)&xsR[xx][dc];
        o[0][0] += p0 * xv.x; o[0][1] += p0 * xv.y; o[0][2] += p0 * xv.z; o[0][3] += p0 * xv.w;
        o[1][0] += p1 * xv.x; o[1][1] += p1 * xv.y; o[1][2] += p1 * xv.z; o[1][3] += p1 * xv.w;
        o[2][0] += p2 * xv.x; o[2][1] += p2 * xv.y; o[2][2] += p2 * xv.z; o[2][3] += p2 * xv.w;
        o[3][0] += p3 * xv.x; o[3][1] += p3 * xv.y; o[3][2] += p3 * xv.z; o[3][3] += p3 * xv.w;
      }
    }
  }

  // ---- epilogue: out[b][d] = (1/SY) * sum_y O[y][d] / l[y] ----
  __syncthreads();
  if (t < YT) l_s[t] = l_i;
  __syncthreads();
  float* Sf = &S[0][0];   // reuse as 8x128 reduction scratch (1056 >= 1024)
  {
    float r0 = 1.f / l_s[yg * 4 + 0], r1 = 1.f / l_s[yg * 4 + 1];
    float r2 = 1.f / l_s[yg * 4 + 2], r3 = 1.f / l_s[yg * 4 + 3];
    #pragma unroll
    for (int j = 0; j < 4; ++j)
      Sf[yg * Dd + dc + j] = o[0][j] * r0 + o[1][j] * r1 + o[2][j] * r2 + o[3][j] * r3;
  }
  __syncthreads();
  if (t < Dd) {
    float s = 0.f;
    #pragma unroll
    for (int g = 0; g < 8; ++g) s += Sf[g * Dd + t];
    atomicAdd(&out[(size_t)b * Dd + t], s * inv_SY);
  }
}

extern "C" void kernel_launch(void* const* d_in, const int* in_sizes, int n_in,
                              void* d_out, int out_size, void* d_ws, size_t ws_size,
                              hipStream_t stream) {
  const float* x = (const float*)d_in[0];   // input_x [B, SX, D]
  const float* y = (const float*)d_in[1];   // input_y [B, SY, D]
  float* visual = (float*)d_out;                       // [B, SX]
  float* out    = (float*)d_out + (size_t)Bn * SX;     // [B, D]

  int n = Bn * SX + Bn * Dd;                // d_out is poisoned 0xAA each call
  zero_kernel<<<(n + 255) / 256, 256, 0, stream>>>((float*)d_out, n);
  attn_kernel<<<Bn * (SY / YT), 256, 0, stream>>>(x, y, visual, out);
}

// Round 2
// 376.543 us; speedup vs baseline: 3.8764x; 3.8764x over previous
//
#include <hip/hip_runtime.h>
#include <math.h>

constexpr int Bn = 16, SY = 2048, SX = 2048, Dd = 128;
constexpr int YT = 64;          // y rows per block (4 waves x 16)
constexpr int XT = 64;          // x cols per tile
constexpr int NXT = SX / XT;    // 32
constexpr int PITCH = 72;       // halfwords; 144B = 9 x 16B -> conflict-free b128

using half8  = __attribute__((ext_vector_type(8))) _Float16;
using half4  = __attribute__((ext_vector_type(4))) _Float16;
using floatx4 = __attribute__((ext_vector_type(4))) float;

__global__ void zero_kernel(float* __restrict__ p, int n) {
  int i = blockIdx.x * 256 + threadIdx.x;
  if (i < n) p[i] = 0.f;
}

__device__ __forceinline__ float sel4(const float* a, int q) {
  float r = a[0];
  r = (q == 1) ? a[1] : r;
  r = (q == 2) ? a[2] : r;
  r = (q == 3) ? a[3] : r;
  return r;
}

// grid 512: blockIdx = b*32 + yblk. Block: 256 thr = 4 waves, wave w owns
// y rows [y0 + 16w, +16). Flash over 32 x-tiles of 64. fp16 MFMA 16x16x32.
__launch_bounds__(256, 3)
__global__ void attn_kernel(const float* __restrict__ x, const float* __restrict__ y,
                            float* __restrict__ visual, float* __restrict__ out) {
  __shared__ _Float16 xT[128 * PITCH];     // [d][xcol], pitch 72 hw
  __shared__ _Float16 Pw[4][16 * PITCH];   // per-wave P, row-major [m][xcol]
  __shared__ float vbuf[4][64];            // per-wave raw-score col sums
  __shared__ float obuf[4][128];           // epilogue out partials

  const int t = threadIdx.x;
  const int w = t >> 6, lane = t & 63;
  const int n = lane & 15, q = lane >> 4;
  const int b = blockIdx.x >> 5;
  const int y0 = (blockIdx.x & 31) * YT;

  // ---- y A-frags into registers, once per block (reused 32x) ----
  // A[m=lane&15][k = q*8 + j], 4 k-steps of 32 cover D=128.
  const float* yrow = y + ((size_t)(b * SY + y0 + w * 16 + n)) * Dd;
  half8 afrag[4];
  #pragma unroll
  for (int k = 0; k < 4; ++k) {
    const float* p4 = yrow + k * 32 + q * 8;
    floatx4 f0 = *(const floatx4*)p4;
    floatx4 f1 = *(const floatx4*)(p4 + 4);
    half8 h;
    h[0] = (_Float16)f0[0]; h[1] = (_Float16)f0[1]; h[2] = (_Float16)f0[2]; h[3] = (_Float16)f0[3];
    h[4] = (_Float16)f1[0]; h[5] = (_Float16)f1[1]; h[6] = (_Float16)f1[2]; h[7] = (_Float16)f1[3];
    afrag[k] = h;
  }

  float m_r[4], l_r[4];
  #pragma unroll
  for (int r = 0; r < 4; ++r) { m_r[r] = -INFINITY; l_r[r] = 0.f; }
  floatx4 acc_o[8];   // O[16 rows][128 d] : 8 d-tiles, row = 4q+reg
  #pragma unroll
  for (int d = 0; d < 8; ++d) acc_o[d] = (floatx4){0.f, 0.f, 0.f, 0.f};

  const float* xb = x + (size_t)b * SX * Dd;
  constexpr float inv_n = 1.0f / 2048.0f;

  for (int xt = 0; xt < NXT; ++xt) {
    __syncthreads();   // barrier A: prev iter's xT/vbuf readers done

    // ---- stage xT (d-major fp16) via strided global reads ----
    // task tau = i*256+t : d = tau&127, xg = tau>>7 (16 groups of 4 xcols)
    #pragma unroll
    for (int i = 0; i < 8; ++i) {
      int tau = i * 256 + t;
      int d = tau & 127, xg = tau >> 7;
      const float* src = xb + ((size_t)(xt * XT + 4 * xg)) * Dd + d;
      half4 h4;
      h4[0] = (_Float16)src[0];
      h4[1] = (_Float16)src[Dd];
      h4[2] = (_Float16)src[2 * Dd];
      h4[3] = (_Float16)src[3 * Dd];
      *(half4*)&xT[d * PITCH + 4 * xg] = h4;
    }

    // ---- S = y @ x^T : 16x64 per wave, B-frags straight from global ----
    floatx4 acc_s[4];
    #pragma unroll
    for (int c = 0; c < 4; ++c) acc_s[c] = (floatx4){0.f, 0.f, 0.f, 0.f};
    #pragma unroll
    for (int k = 0; k < 4; ++k) {
      half8 bf[4];
      #pragma unroll
      for (int c = 0; c < 4; ++c) {
        const float* p4 = xb + (size_t)(xt * XT + 16 * c + n) * Dd + k * 32 + q * 8;
        floatx4 f0 = *(const floatx4*)p4;
        floatx4 f1 = *(const floatx4*)(p4 + 4);
        half8 h;
        h[0] = (_Float16)f0[0]; h[1] = (_Float16)f0[1]; h[2] = (_Float16)f0[2]; h[3] = (_Float16)f0[3];
        h[4] = (_Float16)f1[0]; h[5] = (_Float16)f1[1]; h[6] = (_Float16)f1[2]; h[7] = (_Float16)f1[3];
        bf[c] = h;
      }
      #pragma unroll
      for (int c = 0; c < 4; ++c)
        acc_s[c] = __builtin_amdgcn_mfma_f32_16x16x32_f16(afrag[k], bf[c], acc_s[c], 0, 0, 0);
    }

    // ---- visual: raw-score column sums (before softmax) ----
    {
      float cs4[4];
      #pragma unroll
      for (int c = 0; c < 4; ++c) {
        float cs = acc_s[c][0] + acc_s[c][1] + acc_s[c][2] + acc_s[c][3];
        cs += __shfl_xor(cs, 16);
        cs += __shfl_xor(cs, 32);
        cs4[c] = cs;   // full 16-row sum for col 16c+n, replicated per quad
      }
      vbuf[w][16 * q + n] = sel4(cs4, q);   // quad q publishes c = q
    }

    // ---- online softmax: row max (intra-quad butterflies) ----
    float mt[4], alpha[4];
    #pragma unroll
    for (int r = 0; r < 4; ++r) {
      float mv = fmaxf(fmaxf(acc_s[0][r], acc_s[1][r]), fmaxf(acc_s[2][r], acc_s[3][r]));
      mv = fmaxf(mv, __shfl_xor(mv, 1));
      mv = fmaxf(mv, __shfl_xor(mv, 2));
      mv = fmaxf(mv, __shfl_xor(mv, 4));
      mv = fmaxf(mv, __shfl_xor(mv, 8));
      mt[r] = fmaxf(m_r[r], mv);
      alpha[r] = __expf(m_r[r] - mt[r]);   // 0 on first tile
      m_r[r] = mt[r];
    }

    // ---- P = exp(S-m), row sums, rescale O, write P (fp16, own rows) ----
    #pragma unroll
    for (int r = 0; r < 4; ++r) {
      float rs = 0.f;
      #pragma unroll
      for (int c = 0; c < 4; ++c) {
        float e = __expf(acc_s[c][r] - mt[r]);
        rs += e;
        Pw[w][(4 * q + r) * PITCH + 16 * c + n] = (_Float16)e;
      }
      rs += __shfl_xor(rs, 1);
      rs += __shfl_xor(rs, 2);
      rs += __shfl_xor(rs, 4);
      rs += __shfl_xor(rs, 8);
      l_r[r] = l_r[r] * alpha[r] + rs;
      #pragma unroll
      for (int d = 0; d < 8; ++d) acc_o[d][r] *= alpha[r];
    }

    __syncthreads();   // barrier B: xT staged by all, vbuf complete

    // ---- O += P @ x : A-frag from Pw (own rows), B-frag from xT ----
    #pragma unroll
    for (int k2 = 0; k2 < 2; ++k2) {
      half8 pf = *(const half8*)&Pw[w][n * PITCH + k2 * 32 + q * 8];
      #pragma unroll
      for (int d = 0; d < 8; ++d) {
        half8 xf = *(const half8*)&xT[(16 * d + n) * PITCH + k2 * 32 + q * 8];
        acc_o[d] = __builtin_amdgcn_mfma_f32_16x16x32_f16(pf, xf, acc_o[d], 0, 0, 0);
      }
    }

    // ---- flush visual for this x-tile ----
    if (t < 64) {
      float v = vbuf[0][t] + vbuf[1][t] + vbuf[2][t] + vbuf[3][t];
      atomicAdd(visual + (size_t)b * SX + xt * XT + t, v * inv_n);
    }
  }

  // ---- epilogue: out[b][d] = mean_y O[y][d]/l[y] ----
  float inv_l[4];
  #pragma unroll
  for (int r = 0; r < 4; ++r) inv_l[r] = 1.f / l_r[r];
  float ps[8];
  #pragma unroll
  for (int d = 0; d < 8; ++d) {
    float s = acc_o[d][0] * inv_l[0] + acc_o[d][1] * inv_l[1] +
              acc_o[d][2] * inv_l[2] + acc_o[d][3] * inv_l[3];
    s += __shfl_xor(s, 16);
    s += __shfl_xor(s, 32);
    ps[d] = s;   // 16-row sum for col 16d+n, replicated
  }
  obuf[w][16 * q + n]       = sel4(ps, q);       // d-tiles 0..3
  obuf[w][16 * (q + 4) + n] = sel4(ps + 4, q);   // d-tiles 4..7
  __syncthreads();
  if (t < 128) {
    float s = obuf[0][t] + obuf[1][t] + obuf[2][t] + obuf[3][t];
    atomicAdd(out + (size_t)b * Dd + t, s * inv_n);
  }
}

extern "C" void kernel_launch(void* const* d_in, const int* in_sizes, int n_in,
                              void* d_out, int out_size, void* d_ws, size_t ws_size,
                              hipStream_t stream) {
  const float* x = (const float*)d_in[0];   // [B, SX, D]
  const float* y = (const float*)d_in[1];   // [B, SY, D]
  float* visual = (float*)d_out;                      // [B, SX]
  float* out    = (float*)d_out + (size_t)Bn * SX;    // [B, D]

  int ntot = Bn * SX + Bn * Dd;
  zero_kernel<<<(ntot + 255) / 256, 256, 0, stream>>>((float*)d_out, ntot);
  attn_kernel<<<Bn * (SY / YT), 256, 0, stream>>>(x, y, visual, out);
}